// Round 3
// baseline (168.398 us; speedup 1.0000x reference)
//
#include <hip/hip_runtime.h>

// XCorrExt: B=32, S=160000, N=320, H=160, TAU=257, LAG_CUT=33
// out[b,f,tau-33] = 2*num/(e0 + e_tau + 1e-5), tau in [33,256]
// num[b,f,tau] = sum_n ext[tau+n]*frame[n]; frame[n] = xp[160f+n]
// ext[t] = xp[160f+t] (t<320) | xp[160f+t-160] (t>=320) | f=999,t>=320: x[t-320]
//
// R3: region-pad swizzle phys(i)=i+4*(i/160) -> frame-quad broadcasts across
// the 8 groups of a wave land on banks {4g} (was 8-way conflict on one bank
// quad). Output staged through LDS (stride 232 = 8-bank rotation per group)
// then block-copied fully coalesced (fixes 81 MB -> 28 MB WRITE_SIZE).

#define S_LEN 160000
#define FN    1000
#define NF    32
#define BLOCK 256
#define XSZ   (160 * (NF - 1) + 480)   // 5440 logical floats of signal
#define PHYS(i) ((i) + 4 * ((i) / 160))
#define TOFF  5576                     // > PHYS(XSZ-1)=5571, mult of 4
#define RESST 232                      // res stride: 224 + 8 (bank rotate, 16B-aligned)
#define LDSZ  (NF * RESST)             // 7424 floats = 29 KB (covers TOFF+264=5840)

__global__ __launch_bounds__(BLOCK, 4) void xcorr_kernel(const float* __restrict__ x,
                                                         float* __restrict__ out) {
    __shared__ __align__(16) float lds[LDSZ];
    const int tid   = threadIdx.x;
    const int b     = blockIdx.y;
    const int fbase = blockIdx.x * NF;
    const long bOff = (long)b * S_LEN;
    const int gbase = fbase * 160;

    // ---------------- stage shared X, swizzled (coalesced float4 reads) --------
    for (int i = 4 * tid; i < XSZ; i += 4 * BLOCK) {
        const int gx = gbase + i;
        const int pa = PHYS(i);        // quads never cross a 160-region (4|160)
        if (gx + 3 < S_LEN) {
            *(float4*)&lds[pa] = *(const float4*)&x[bOff + gx];
        } else {
#pragma unroll
            for (int e = 0; e < 4; ++e)
                lds[pa + e] = (gx + e < S_LEN) ? x[bOff + gx + e] : 0.f;
        }
    }
    // T[j] = ext_{999}[320+j] = x[b, j]  (only the block containing f=999)
    if (fbase + NF > FN - 1) {
        for (int j = tid; j < 264; j += BLOCK)
            lds[TOFF + j] = x[bOff + j];
    }
    __syncthreads();

    // ---------------- compute ----------------
    const int g    = tid >> 3;         // frame group 0..31
    const int r    = tid & 7;          // lane in group
    const int f    = fbase + g;
    const bool useT = (f == FN - 1);
    const int tau0 = 33 + 28 * r;
    const int wb   = tau0 - 1;         // 32+28r, multiple of 4
    const int xg   = 164 * g;          // swizzled group base (160g + 4g)
    // ext addr = w + C, C selected by w-range (fold + region pad folded in):
    const int C0 = xg;                             // w in [0,160)
    const int C1 = xg + 4;                         // w in [160,320)
    const int C2 = useT ? (TOFF - 320) : (xg - 156);  // w in [320,480): fold -160, region+1
    const int C3 = useT ? (TOFF - 320) : (xg - 152);  // w in [480,580): fold -160, region+2

    float acc[28];
#pragma unroll
    for (int c = 0; c < 28; ++c) acc[c] = 0.f;
    float W[32];       // rotating window: ext[wb + o] at slot o & 31
    float FQ[4][4];    // frame quad k at slot k & 3

#pragma unroll
    for (int j = 0; j < 8; ++j) {      // w = wb..wb+31 <= 256 < 320: C0/C1 only
        const int w = wb + 4 * j;
        const float4 q = *(const float4*)&lds[w + ((w < 160) ? C0 : C1)];
        W[4*j] = q.x; W[4*j+1] = q.y; W[4*j+2] = q.z; W[4*j+3] = q.w;
    }
#pragma unroll
    for (int j = 0; j < 4; ++j) {      // frame[0..15], region 0
        const float4 q = *(const float4*)&lds[xg + 4 * j];
        FQ[j][0] = q.x; FQ[j][1] = q.y; FQ[j][2] = q.z; FQ[j][3] = q.w;
    }

    float Tsum = 0.f, e0 = 0.f;

#pragma unroll 1
    for (int ko = 0; ko < 10; ++ko) {
#pragma unroll
        for (int ki = 0; ki < 8; ++ki) {
            const int k = ko * 8 + ki;
#pragma unroll
            for (int d = 0; d < 4; ++d) {
                const float fv = FQ[ki & 3][d];
#pragma unroll
                for (int c = 0; c < 28; ++c)
                    acc[c] = fmaf(fv, W[(1 + 4 * ki + d + c) & 31], acc[c]);
                const float tv = W[(1 + 4 * ki + d) & 31];   // ext[tau0+4k+d]
                Tsum = fmaf(tv, tv, Tsum);                   // offsets 1..320
                e0   = fmaf(fv, fv, e0);                     // frame energy
            }
            // prefetch ext quad k+8 (w = wb+4k+32 .. +3, slots (4ki..4ki+3)&31)
            {
                const int w = wb + 4 * k + 32;
                const int cc = (w < 160) ? C0 : (w < 320) ? C1 : (w < 480) ? C2 : C3;
                const float4 q = *(const float4*)&lds[w + cc];
                W[(4*ki + 0) & 31] = q.x; W[(4*ki + 1) & 31] = q.y;
                W[(4*ki + 2) & 31] = q.z; W[(4*ki + 3) & 31] = q.w;
            }
            // prefetch frame quad k+4 (addr fully static off xg: zero VALU)
            {
                const int fo = 4 * k + 16;
                const float4 q = *(const float4*)&lds[xg + fo + 4 * (fo / 160)];
                FQ[ki & 3][0] = q.x; FQ[ki & 3][1] = q.y;
                FQ[ki & 3][2] = q.z; FQ[ki & 3][3] = q.w;
            }
        }
    }

    // ---------------- epilogue: e_tau chain + normalize ----------------
    float res[28];
    {
        float et = Tsum;               // e_tau[tau0]
#pragma unroll
        for (int c = 0; c < 28; ++c) {
            const float den = e0 + et + 1e-5f;
            res[c] = 2.f * acc[c] * __builtin_amdgcn_rcpf(den);
            if (c < 27) {
                const int u = tau0 + c;                       // ext[u], u < 320
                const float pv = lds[xg + u + ((u >= 160) ? 4 : 0)];
                const int v = u + 160;                        // fold of ext[u+320]
                const float sv = useT ? lds[TOFF + u]
                                      : lds[xg + v + ((v >= 320) ? 8 : 4)];
                et += sv * sv - pv * pv;
            }
        }
    }
    __syncthreads();                   // all X reads done; reuse lds for res
    {
        float* R = &lds[RESST * g + 28 * r];
#pragma unroll
        for (int q = 0; q < 7; ++q)
            *(float4*)&R[4 * q] = make_float4(res[4*q], res[4*q+1], res[4*q+2], res[4*q+3]);
    }
    __syncthreads();

    // ---------------- coalesced store: 7 x 1KB-per-wave float4 writes ---------
    const long outBase = ((long)b * FN + fbase) * 224;
#pragma unroll
    for (int j = 0; j < 7; ++j) {
        const int qi = tid + BLOCK * j;    // quad index 0..1791
        const int gg = qi / 56;            // group (56 quads = 224 floats each)
        const int cc = 4 * (qi - 56 * gg);
        if (fbase + gg < FN)
            *(float4*)&out[outBase + 224 * gg + cc] = *(const float4*)&lds[RESST * gg + cc];
    }
}

extern "C" void kernel_launch(void* const* d_in, const int* in_sizes, int n_in,
                              void* d_out, int out_size, void* d_ws, size_t ws_size,
                              hipStream_t stream) {
    const float* x = (const float*)d_in[0];
    float* out = (float*)d_out;
    dim3 grid((FN + NF - 1) / NF, 32);   // (32, 32) = 1024 blocks = 4 per CU
    dim3 block(BLOCK);
    hipLaunchKernelGGL(xcorr_kernel, grid, block, 0, stream, x, out);
}

// Round 4
// 133.432 us; speedup vs baseline: 1.2620x; 1.2620x over previous
//
#include <hip/hip_runtime.h>

// XCorrExt: B=32, S=160000, N=320, H=160, TAU=257, LAG_CUT=33
// out[b,f,tau-33] = 2*num/(e0 + e_tau + 1e-5), tau in [33,256]
// num[b,f,tau] = sum_n ext[tau+n]*frame[n]; frame[n] = xp[160f+n]
// ext[t] = xp[160f+t] (t<320) | xp[160f+t-160] (t>=320) | f=999,t>=320: x[t-320]
//
// R4: fix register spilling (R2/R3 showed VGPR_Count=64 vs ~85 live ->
// scratch traffic 53..300 MB). amdgpu_waves_per_eu(4,4) pins the allocator
// at 4 waves/EU = 128-VGPR budget (grid is exactly 4 blocks/CU). FQ cut to
// 2 quads (distance-2 prefetch), epilogue chunked so res live = 4. Direct
// float4 stores (L2 write-back assembles full lines). Keep R3's region-pad
// swizzle phys(i)=i+4*(i/160): frame-quad broadcasts land on banks {4g}.

#define S_LEN 160000
#define FN    1000
#define NF    32
#define BLOCK 256
#define XSZ   (160 * (NF - 1) + 480)   // 5440 logical floats of signal
#define PHYS(i) ((i) + 4 * ((i) / 160))
#define TOFF  5576                     // > PHYS(XSZ-1)+3, multiple of 4
#define LDSZ  (TOFF + 264)             // 5840 floats = 23.4 KB

__global__ __launch_bounds__(BLOCK)
__attribute__((amdgpu_waves_per_eu(4, 4)))
void xcorr_kernel(const float* __restrict__ x, float* __restrict__ out) {
    __shared__ __align__(16) float lds[LDSZ];
    const int tid   = threadIdx.x;
    const int b     = blockIdx.y;
    const int fbase = blockIdx.x * NF;
    const long bOff = (long)b * S_LEN;
    const int gbase = fbase * 160;

    // ---------------- stage shared X, swizzled (coalesced float4 reads) --------
    for (int i = 4 * tid; i < XSZ; i += 4 * BLOCK) {
        const int gx = gbase + i;
        const int pa = PHYS(i);        // quads never cross a 160-region (4|160)
        if (gx + 3 < S_LEN) {
            *(float4*)&lds[pa] = *(const float4*)&x[bOff + gx];
        } else {
#pragma unroll
            for (int e = 0; e < 4; ++e)
                lds[pa + e] = (gx + e < S_LEN) ? x[bOff + gx + e] : 0.f;
        }
    }
    // T[j] = ext_{999}[320+j] = x[b, j]  (only the block containing f=999)
    if (fbase + NF > FN - 1) {
        for (int j = tid; j < 264; j += BLOCK)
            lds[TOFF + j] = x[bOff + j];
    }
    __syncthreads();

    // ---------------- compute ----------------
    const int g    = tid >> 3;         // frame group 0..31
    const int r    = tid & 7;          // lane in group
    const int f    = fbase + g;
    const bool useT = (f == FN - 1);
    const int tau0 = 33 + 28 * r;
    const int wb   = tau0 - 1;         // 32+28r, multiple of 4
    const int xg   = 164 * g;          // swizzled group base (160g + 4g)
    // ext addr = w + C, C selected by w-range (fold + region pad folded in):
    const int C0 = xg;                                // w in [0,160)
    const int C1 = xg + 4;                            // w in [160,320)
    const int C2 = useT ? (TOFF - 320) : (xg - 156);  // w in [320,480)
    const int C3 = useT ? (TOFF - 320) : (xg - 152);  // w in [480,580)

    float acc[28];
#pragma unroll
    for (int c = 0; c < 28; ++c) acc[c] = 0.f;
    float W[32];       // rotating window: ext[wb + o] at slot o & 31
    float FQ[2][4];    // frame quad k at slot k & 1 (distance-2 prefetch)

#pragma unroll
    for (int j = 0; j < 8; ++j) {      // w = wb..wb+31 <= 259 < 320: C0/C1 only
        const int w = wb + 4 * j;
        const float4 q = *(const float4*)&lds[w + ((w < 160) ? C0 : C1)];
        W[4*j] = q.x; W[4*j+1] = q.y; W[4*j+2] = q.z; W[4*j+3] = q.w;
    }
#pragma unroll
    for (int j = 0; j < 2; ++j) {      // frame quads 0,1 (region 0)
        const float4 q = *(const float4*)&lds[xg + 4 * j];
        FQ[j][0] = q.x; FQ[j][1] = q.y; FQ[j][2] = q.z; FQ[j][3] = q.w;
    }

    float Tsum = 0.f, e0 = 0.f;

#pragma unroll 1
    for (int ko = 0; ko < 10; ++ko) {
#pragma unroll
        for (int ki = 0; ki < 8; ++ki) {
            const int k = ko * 8 + ki;
#pragma unroll
            for (int d = 0; d < 4; ++d) {
                const float fv = FQ[ki & 1][d];
#pragma unroll
                for (int c = 0; c < 28; ++c)
                    acc[c] = fmaf(fv, W[(1 + 4 * ki + d + c) & 31], acc[c]);
                const float tv = W[(1 + 4 * ki + d) & 31];   // ext[tau0+4k+d]
                Tsum = fmaf(tv, tv, Tsum);                   // offsets 1..320
                e0   = fmaf(fv, fv, e0);                     // frame energy
            }
            // prefetch ext quad k+8 (w = wb+4k+32 .. +3, slots (4ki..4ki+3)&31)
            {
                const int w = wb + 4 * k + 32;
                const int cc = (w < 160) ? C0 : (w < 320) ? C1 : (w < 480) ? C2 : C3;
                const float4 q = *(const float4*)&lds[w + cc];
                W[(4*ki + 0) & 31] = q.x; W[(4*ki + 1) & 31] = q.y;
                W[(4*ki + 2) & 31] = q.z; W[(4*ki + 3) & 31] = q.w;
            }
            // prefetch frame quad k+2 into slot (k+2)&1 == ki&1 (used round k+2)
            {
                const int fo = 4 * k + 8;
                const float4 q = *(const float4*)&lds[xg + fo + 4 * (fo / 160)];
                FQ[ki & 1][0] = q.x; FQ[ki & 1][1] = q.y;
                FQ[ki & 1][2] = q.z; FQ[ki & 1][3] = q.w;
            }
        }
    }

    // ---------------- epilogue: e_tau chain + normalize, chunked stores -------
    if (f < FN) {
        float* op = &out[((long)(b * FN + f)) * 224 + 28 * r];
        float et = Tsum;               // e_tau[tau0]
#pragma unroll
        for (int q = 0; q < 7; ++q) {
            float res[4];
#pragma unroll
            for (int e = 0; e < 4; ++e) {
                const int c = 4 * q + e;
                const float den = e0 + et + 1e-5f;
                res[e] = 2.f * acc[c] * __builtin_amdgcn_rcpf(den);
                if (c < 27) {
                    const int u = tau0 + c;                   // ext[u], u < 320
                    const float pv = lds[xg + u + ((u >= 160) ? 4 : 0)];
                    const int v = u + 160;                    // fold of ext[u+320]
                    const float sv = useT ? lds[TOFF + u]
                                          : lds[xg + v + ((v >= 320) ? 8 : 4)];
                    et += sv * sv - pv * pv;
                }
            }
            *(float4*)&op[4 * q] = make_float4(res[0], res[1], res[2], res[3]);
        }
    }
}

extern "C" void kernel_launch(void* const* d_in, const int* in_sizes, int n_in,
                              void* d_out, int out_size, void* d_ws, size_t ws_size,
                              hipStream_t stream) {
    const float* x = (const float*)d_in[0];
    float* out = (float*)d_out;
    dim3 grid((FN + NF - 1) / NF, 32);   // (32, 32) = 1024 blocks = 4 per CU
    dim3 block(BLOCK);
    hipLaunchKernelGGL(xcorr_kernel, grid, block, 0, stream, x, out);
}